// Round 11
// baseline (452.621 us; speedup 1.0000x reference)
//
#include <hip/hip_runtime.h>
#include <hip/hip_bf16.h>
#include <hip/hip_fp16.h>
#include <cstdint>

#define NCHUNK 32          // edge chunks (chist table = NCHUNK*N*4B = 12.8MB)
#define NRANGE 8           // node ranges (rangeSize ~12.5k -> 50KB LDS hist)
#define SCAT_PER 16        // edges per thread in scatter

// ---------------- CSR build (zero global atomics) ----------------

// Block (r,c): LDS-histogram chunk c's edges whose dst is in range r.
// LDS atomicAdd return = edge's local rank within (chunk, dst); coalesced store.
__global__ void __launch_bounds__(256)
k_hist_lds(const int* __restrict__ dstv, int E, int chunkSize, int n, int rangeSize,
           int* __restrict__ chist, int* __restrict__ rank) {
    __shared__ int lh[12800];
    int c = blockIdx.x & (NCHUNK - 1);
    int r = blockIdx.x / NCHUNK;
    int base = r * rangeSize;
    int rsz = min(rangeSize, n - base);
    if (rsz <= 0) return;
    int t = threadIdx.x;
    for (int i = t; i < rsz; i += 256) lh[i] = 0;
    __syncthreads();
    int e0 = c * chunkSize;
    int e1 = min(e0 + chunkSize, E);
    for (int i = e0 + t; i < e1; i += 256) {
        int d = dstv[i];
        unsigned rel = (unsigned)(d - base);
        if (rel < (unsigned)rsz) rank[i] = atomicAdd(&lh[rel], 1);
    }
    __syncthreads();
    int* out = chist + (size_t)c * n + base;
    for (int i = t; i < rsz; i += 256) out[i] = lh[i];
}

// per-node exclusive prefix across the NCHUNK counts (in place); deg = total
__global__ void k_chist_scan(int* __restrict__ chist, int n, int* __restrict__ deg) {
    int d = blockIdx.x * blockDim.x + threadIdx.x;
    if (d >= n) return;
    int sum = 0;
#pragma unroll
    for (int c = 0; c < NCHUNK; ++c) {
        int v = chist[(size_t)c * n + d];
        chist[(size_t)c * n + d] = sum;
        sum += v;
    }
    deg[d] = sum;
}

__global__ void k_scan1(const int* __restrict__ deg, int n, int* __restrict__ bsums) {
    __shared__ int s[256];
    int t = threadIdx.x;
    int i = blockIdx.x * 256 + t;
    int v = (i < n) ? deg[i] : 0;
    s[t] = v; __syncthreads();
    for (int off = 128; off > 0; off >>= 1) {
        if (t < off) s[t] += s[t + off];
        __syncthreads();
    }
    if (t == 0) bsums[blockIdx.x] = s[0];
}

// single block, inclusive->exclusive scan of up to 512 block sums
__global__ void k_scan2(const int* __restrict__ bsums, int nb, int* __restrict__ boffs) {
    __shared__ int s[512];
    int t = threadIdx.x;
    int v = (t < nb) ? bsums[t] : 0;
    s[t] = v; __syncthreads();
    for (int off = 1; off < 512; off <<= 1) {
        int nv = (t >= off) ? s[t - off] : 0;
        __syncthreads();
        s[t] += nv;
        __syncthreads();
    }
    if (t < nb) boffs[t] = s[t] - v;  // exclusive
}

__global__ void k_scan3(const int* __restrict__ deg, int n, const int* __restrict__ boffs,
                        int* __restrict__ rowst) {
    __shared__ int s[256];
    int t = threadIdx.x;
    int i = blockIdx.x * 256 + t;
    int v = (i < n) ? deg[i] : 0;
    s[t] = v; __syncthreads();
    for (int off = 1; off < 256; off <<= 1) {
        int nv = (t >= off) ? s[t - off] : 0;
        __syncthreads();
        s[t] += nv;
        __syncthreads();
    }
    int incl = s[t] + boffs[blockIdx.x];
    if (i < n) {
        rowst[i] = incl - v;
        if (i == n - 1) rowst[n] = incl;
    }
}

// atomic-free scatter: position = rowst[d] + chist[c][d] + local_rank.
// Blocks are per-chunk, so the chist slice (400KB) is L2-resident for the block.
__global__ void k_scatter(const int* __restrict__ src, const int* __restrict__ dst,
                          const int* __restrict__ rank, const int* __restrict__ rowst,
                          const int* __restrict__ chist, int n, int E, int chunkSize,
                          int blocksPerChunk, int* __restrict__ col) {
    int c = blockIdx.x / blocksPerChunk;
    int lb = blockIdx.x % blocksPerChunk;
    const int* cslice = chist + (size_t)c * n;
    int cbeg = c * chunkSize;
    int cend = min(cbeg + chunkSize, E);
    int base = cbeg + (lb * 256 + threadIdx.x) * SCAT_PER;
    if (base + SCAT_PER <= cend) {
        int4 d[4], s[4], r[4];
#pragma unroll
        for (int k = 0; k < 4; ++k) {
            d[k] = *reinterpret_cast<const int4*>(dst + base + k * 4);
            s[k] = *reinterpret_cast<const int4*>(src + base + k * 4);
            r[k] = *reinterpret_cast<const int4*>(rank + base + k * 4);
        }
        const int* dd = reinterpret_cast<const int*>(d);
        const int* ss = reinterpret_cast<const int*>(s);
        const int* rr = reinterpret_cast<const int*>(r);
        int p[16];
#pragma unroll
        for (int k = 0; k < 16; ++k) p[k] = rowst[dd[k]] + cslice[dd[k]] + rr[k];
#pragma unroll
        for (int k = 0; k < 16; ++k) col[p[k]] = ss[k];
    } else {
        for (int i = base; i < cend; ++i)
            col[rowst[dst[i]] + cslice[dst[i]] + rank[i]] = src[i];
    }
}

// ---------------- per-layer kernels ----------------

__device__ __forceinline__ float lane_bcast(float v, int k) {
    return __int_as_float(__builtin_amdgcn_readlane(__float_as_int(v), k));
}

// Zero-LDS GEMM: each wave owns 16 nodes; lane holds W column pair in 64 VGPRs;
// x broadcast via readlane (static index, fully unrolled).
__global__ void __launch_bounds__(256)
k_gemm_alpha(const float* __restrict__ x, const float* __restrict__ W,
             const float* __restrict__ a_src, const float* __restrict__ a_dst,
             __half* __restrict__ h16, float* __restrict__ alpha_src,
             float* __restrict__ alpha_dst, int n) {
    int lane = threadIdx.x & 63;
    int wave = threadIdx.x >> 6;
    int j2 = lane * 2;              // flattened out channel pair = head*32 + c
    int nbase = blockIdx.x * 64 + wave * 16;

    float2 wr[32];
#pragma unroll
    for (int k = 0; k < 32; ++k)
        wr[k] = *reinterpret_cast<const float2*>(W + k * 128 + j2);
    float2 as2 = *reinterpret_cast<const float2*>(a_src + j2);
    float2 ad2 = *reinterpret_cast<const float2*>(a_dst + j2);

    float xr[16];
#pragma unroll
    for (int m = 0; m < 16; ++m) {
        int node = nbase + m;
        xr[m] = (node < n) ? x[(size_t)node * 32 + (lane & 31)] : 0.f;
    }

#pragma unroll
    for (int m = 0; m < 16; ++m) {
        int node = nbase + m;
        if (node >= n) continue;     // wave-uniform guard
        float acc0 = 0.f, acc1 = 0.f;
#pragma unroll
        for (int k = 0; k < 32; ++k) {
            float xv = lane_bcast(xr[m], k);
            acc0 += xv * wr[k].x;
            acc1 += xv * wr[k].y;
        }
        *reinterpret_cast<__half2*>(h16 + (size_t)node * 128 + j2) =
            __floats2half2_rn(acc0, acc1);
        float ps = acc0 * as2.x + acc1 * as2.y;
        float pd = acc0 * ad2.x + acc1 * ad2.y;
#pragma unroll
        for (int mm = 1; mm < 16; mm <<= 1) {
            ps += __shfl_xor(ps, mm, 64);
            pd += __shfl_xor(pd, mm, 64);
        }
        if ((lane & 15) == 0) {
            int head = lane >> 4;
            alpha_src[node * 4 + head] = ps;
            alpha_dst[node * 4 + head] = pd;
        }
    }
}

__device__ __forceinline__ float lrelu_exp(float e) {
    e = e > 0.f ? e : 0.2f * e;
    return __expf(e);
}

// one wave per dst node; 4 edges per wave via 16-lane groups, 2 edges in flight
// per group (8 rows in flight/wave). Lane q loads uint4 = 8 fp16 channels.
// single-pass softmax + self loop + head-mean + bias + elu.
__global__ void k_agg(const __half* __restrict__ h16, const float* __restrict__ asrc,
                      const float* __restrict__ adst, const int* __restrict__ rowst,
                      const int* __restrict__ col, const float* __restrict__ bias,
                      float* __restrict__ out, int n) {
    int wid = (int)((blockIdx.x * (size_t)blockDim.x + threadIdx.x) >> 6);
    if (wid >= n) return;
    int lane = threadIdx.x & 63;
    int g = lane >> 4;          // edge group 0..3
    int q = lane & 15;          // 16 lanes per edge; lane q -> channels 8q..8q+7
    int head = q >> 2;
    float ad = adst[wid * 4 + head];

    float acc[8] = {0.f, 0.f, 0.f, 0.f, 0.f, 0.f, 0.f, 0.f};
    float s = 0.f;

    if (g == 0) {  // self loop counted once (group 0)
        float w = lrelu_exp(asrc[wid * 4 + head] + ad);
        uint4 v = *reinterpret_cast<const uint4*>(h16 + (size_t)wid * 128 + q * 8);
        const __half2* hp = reinterpret_cast<const __half2*>(&v);
        s = w;
#pragma unroll
        for (int k = 0; k < 4; ++k) {
            float2 f = __half22float2(hp[k]);
            acc[2 * k]     += w * f.x;
            acc[2 * k + 1] += w * f.y;
        }
    }

    int beg = rowst[wid], end = rowst[wid + 1];
    int i = beg + g;
    for (; i + 4 < end; i += 8) {           // 2 edges in flight per group
        int s0 = col[i];
        int s1 = col[i + 4];
        float x0 = asrc[s0 * 4 + head];
        float x1 = asrc[s1 * 4 + head];
        uint4 v0 = *reinterpret_cast<const uint4*>(h16 + (size_t)s0 * 128 + q * 8);
        uint4 v1 = *reinterpret_cast<const uint4*>(h16 + (size_t)s1 * 128 + q * 8);
        float w0 = lrelu_exp(x0 + ad);
        float w1 = lrelu_exp(x1 + ad);
        s += w0 + w1;
        const __half2* h0 = reinterpret_cast<const __half2*>(&v0);
        const __half2* h1 = reinterpret_cast<const __half2*>(&v1);
#pragma unroll
        for (int k = 0; k < 4; ++k) {
            float2 f0 = __half22float2(h0[k]);
            float2 f1 = __half22float2(h1[k]);
            acc[2 * k]     += w0 * f0.x + w1 * f1.x;
            acc[2 * k + 1] += w0 * f0.y + w1 * f1.y;
        }
    }
    if (i < end) {                          // per-group tail (0 or 1 edge)
        int s0 = col[i];
        float w = lrelu_exp(asrc[s0 * 4 + head] + ad);
        uint4 v = *reinterpret_cast<const uint4*>(h16 + (size_t)s0 * 128 + q * 8);
        const __half2* hp = reinterpret_cast<const __half2*>(&v);
        s += w;
#pragma unroll
        for (int k = 0; k < 4; ++k) {
            float2 f = __half22float2(hp[k]);
            acc[2 * k]     += w * f.x;
            acc[2 * k + 1] += w * f.y;
        }
    }

    // combine the 4 groups
    s += __shfl_xor(s, 16, 64);
    s += __shfl_xor(s, 32, 64);
#pragma unroll
    for (int k = 0; k < 8; ++k) {
        acc[k] += __shfl_xor(acc[k], 16, 64);
        acc[k] += __shfl_xor(acc[k], 32, 64);
    }
    float inv = 1.f / s;
#pragma unroll
    for (int k = 0; k < 8; ++k) acc[k] *= inv;
    // head mean
#pragma unroll
    for (int k = 0; k < 8; ++k) {
        acc[k] += __shfl_xor(acc[k], 4, 64);
        acc[k] += __shfl_xor(acc[k], 8, 64);
    }
    if (lane < 4) {
        float o[8];
#pragma unroll
        for (int k = 0; k < 8; ++k) {
            float v = acc[k] * 0.25f + bias[lane * 8 + k];
            o[k] = v > 0.f ? v : (__expf(v) - 1.f);
        }
        float4* op = reinterpret_cast<float4*>(&out[(size_t)wid * 32 + lane * 8]);
        op[0] = make_float4(o[0], o[1], o[2], o[3]);
        op[1] = make_float4(o[4], o[5], o[6], o[7]);
    }
}

// ---------------- launch ----------------

extern "C" void kernel_launch(void* const* d_in, const int* in_sizes, int n_in,
                              void* d_out, int out_size, void* d_ws, size_t ws_size,
                              hipStream_t stream) {
    const float* x       = (const float*)d_in[0];
    const int*   ei      = (const int*)d_in[1];   // [2,E] int32
    const float* Ws      = (const float*)d_in[3]; // [3,32,128]
    const float* att_src = (const float*)d_in[4]; // [3,4,32]
    const float* att_dst = (const float*)d_in[5];
    const float* bias    = (const float*)d_in[6]; // [3,32]

    int N = in_sizes[0] / 32;
    int E = in_sizes[1] / 2;
    const int* srcv = ei;
    const int* dstv = ei + E;

    // workspace layout (~69MB)
    float* fws   = (float*)d_ws;
    __half* h16  = (__half*)fws;                        // N*128 halves
    float* asrc  = (float*)(h16 + (size_t)N * 128);     // N*4
    float* adst  = asrc + (size_t)N * 4;                // N*4
    float* xbuf  = adst + (size_t)N * 4;                // N*32
    int*   deg    = (int*)(xbuf + (size_t)N * 32);      // N
    int*   rowst  = deg + N;                            // N+1
    int*   bsums  = rowst + N + 1;                      // 512
    int*   boffs  = bsums + 512;                        // 512
    int*   col    = boffs + 512;                        // E
    int*   rank   = col + E;                            // E
    int*   chist  = rank + E;                           // NCHUNK*N

    int nb256 = (N + 255) / 256;                 // <=512 for scan2
    int gemmBlocks = (N + 63) / 64;
    int rangeSize = (N + NRANGE - 1) / NRANGE;   // 12500 (<=12800 LDS)
    int chunkSize = (E + NCHUNK - 1) / NCHUNK;   // 50000
    int blocksPerChunk = (chunkSize + 256 * SCAT_PER - 1) / (256 * SCAT_PER);

    // CSR build: LDS hist (+rank) -> chunk prefix -> node scan -> scatter
    k_hist_lds<<<NRANGE * NCHUNK, 256, 0, stream>>>(dstv, E, chunkSize, N, rangeSize,
                                                    chist, rank);
    k_chist_scan<<<nb256, 256, 0, stream>>>(chist, N, deg);
    k_scan1<<<nb256, 256, 0, stream>>>(deg, N, bsums);
    k_scan2<<<1, 512, 0, stream>>>(bsums, nb256, boffs);
    k_scan3<<<nb256, 256, 0, stream>>>(deg, N, boffs, rowst);
    k_scatter<<<NCHUNK * blocksPerChunk, 256, 0, stream>>>(
        srcv, dstv, rank, rowst, chist, N, E, chunkSize, blocksPerChunk, col);

    for (int l = 0; l < 3; ++l) {
        const float* xin = (l == 0) ? x : xbuf;
        float* xout = (l == 2) ? (float*)d_out : xbuf;
        k_gemm_alpha<<<gemmBlocks, 256, 0, stream>>>(
            xin, Ws + (size_t)l * 32 * 128, att_src + l * 128, att_dst + l * 128,
            h16, asrc, adst, N);
        k_agg<<<(N + 3) / 4, 256, 0, stream>>>(
            h16, asrc, adst, rowst, col, bias + l * 32, xout, N);
    }
}

// Round 12
// 403.056 us; speedup vs baseline: 1.1230x; 1.1230x over previous
//
#include <hip/hip_runtime.h>
#include <hip/hip_bf16.h>
#include <hip/hip_fp16.h>
#include <cstdint>

#define NCHUNK 40          // edge chunks (chist = NCHUNK*N*4B = 16MB)
#define NRANGE 16          // node ranges (6250 nodes -> 25KB LDS, 6 blocks/CU)
#define RSIZE_MAX 6400
#define SCAT_PER 16        // edges per thread in scatter

// ---------------- CSR build (zero global atomics) ----------------

// per-node exclusive prefix across the NCHUNK counts (in place); deg = total
__global__ void k_chist_scan(int* __restrict__ chist, int n, int* __restrict__ deg) {
    int d = blockIdx.x * blockDim.x + threadIdx.x;
    if (d >= n) return;
    int sum = 0;
#pragma unroll
    for (int c = 0; c < NCHUNK; ++c) {
        int v = chist[(size_t)c * n + d];
        chist[(size_t)c * n + d] = sum;
        sum += v;
    }
    deg[d] = sum;
}

__global__ void k_scan1(const int* __restrict__ deg, int n, int* __restrict__ bsums) {
    __shared__ int s[256];
    int t = threadIdx.x;
    int i = blockIdx.x * 256 + t;
    int v = (i < n) ? deg[i] : 0;
    s[t] = v; __syncthreads();
    for (int off = 128; off > 0; off >>= 1) {
        if (t < off) s[t] += s[t + off];
        __syncthreads();
    }
    if (t == 0) bsums[blockIdx.x] = s[0];
}

// single block, inclusive->exclusive scan of up to 512 block sums
__global__ void k_scan2(const int* __restrict__ bsums, int nb, int* __restrict__ boffs) {
    __shared__ int s[512];
    int t = threadIdx.x;
    int v = (t < nb) ? bsums[t] : 0;
    s[t] = v; __syncthreads();
    for (int off = 1; off < 512; off <<= 1) {
        int nv = (t >= off) ? s[t - off] : 0;
        __syncthreads();
        s[t] += nv;
        __syncthreads();
    }
    if (t < nb) boffs[t] = s[t] - v;  // exclusive
}

__global__ void k_scan3(const int* __restrict__ deg, int n, const int* __restrict__ boffs,
                        int* __restrict__ rowst) {
    __shared__ int s[256];
    int t = threadIdx.x;
    int i = blockIdx.x * 256 + t;
    int v = (i < n) ? deg[i] : 0;
    s[t] = v; __syncthreads();
    for (int off = 1; off < 256; off <<= 1) {
        int nv = (t >= off) ? s[t - off] : 0;
        __syncthreads();
        s[t] += nv;
        __syncthreads();
    }
    int incl = s[t] + boffs[blockIdx.x];
    if (i < n) {
        rowst[i] = incl - v;
        if (i == n - 1) rowst[n] = incl;
    }
}

// atomic-free scatter: position = rowst[d] + chist[c][d] + local_rank.
// Blocks are per-chunk, so the chist slice (400KB) is L2-resident for the block.
__global__ void k_scatter(const int* __restrict__ src, const int* __restrict__ dst,
                          const int* __restrict__ rank, const int* __restrict__ rowst,
                          const int* __restrict__ chist, int n, int E, int chunkSize,
                          int blocksPerChunk, int* __restrict__ col) {
    int c = blockIdx.x / blocksPerChunk;
    int lb = blockIdx.x % blocksPerChunk;
    const int* cslice = chist + (size_t)c * n;
    int cbeg = c * chunkSize;
    int cend = min(cbeg + chunkSize, E);
    int base = cbeg + (lb * 256 + threadIdx.x) * SCAT_PER;
    if (base + SCAT_PER <= cend) {
        int4 d[4], s[4], r[4];
#pragma unroll
        for (int k = 0; k < 4; ++k) {
            d[k] = *reinterpret_cast<const int4*>(dst + base + k * 4);
            s[k] = *reinterpret_cast<const int4*>(src + base + k * 4);
            r[k] = *reinterpret_cast<const int4*>(rank + base + k * 4);
        }
        const int* dd = reinterpret_cast<const int*>(d);
        const int* ss = reinterpret_cast<const int*>(s);
        const int* rr = reinterpret_cast<const int*>(r);
        int p[16];
#pragma unroll
        for (int k = 0; k < 16; ++k) p[k] = rowst[dd[k]] + cslice[dd[k]] + rr[k];
#pragma unroll
        for (int k = 0; k < 16; ++k) col[p[k]] = ss[k];
    } else {
        for (int i = base; i < cend; ++i)
            col[rowst[dst[i]] + cslice[dst[i]] + rank[i]] = src[i];
    }
}

// ---------------- per-layer kernels ----------------

__device__ __forceinline__ float lane_bcast(float v, int k) {
    return __int_as_float(__builtin_amdgcn_readlane(__float_as_int(v), k));
}

// Fused (layer 0): blocks [0,gemmBlocks) do the zero-LDS GEMM+alpha; blocks
// beyond do the range*chunk LDS histogram with batched (8/thread) edge loads.
// LDS atomicAdd return = edge's local rank within (chunk, dst).
__global__ void __launch_bounds__(256)
k_gemm_hist(const float* __restrict__ x, const float* __restrict__ W,
            const float* __restrict__ a_src, const float* __restrict__ a_dst,
            __half* __restrict__ h16, float* __restrict__ alpha_src,
            float* __restrict__ alpha_dst, int n,
            const int* __restrict__ dstv, int E, int chunkSize, int rangeSize,
            int* __restrict__ chist, int* __restrict__ rank, int gemmBlocks) {
    __shared__ int lh[RSIZE_MAX];
    if ((int)blockIdx.x >= gemmBlocks) {
        int b = blockIdx.x - gemmBlocks;
        int c = b % NCHUNK;
        int r = b / NCHUNK;
        int base = r * rangeSize;
        int rsz = min(rangeSize, n - base);
        if (rsz <= 0) return;
        int t = threadIdx.x;
        for (int i = t; i < rsz; i += 256) lh[i] = 0;
        __syncthreads();
        int e0 = c * chunkSize;                 // chunkSize multiple of 8
        int e1 = min(e0 + chunkSize, E);
        for (int i = e0 + t * 8; i + 8 <= e1; i += 2048) {
            int4 d0 = *reinterpret_cast<const int4*>(dstv + i);
            int4 d1 = *reinterpret_cast<const int4*>(dstv + i + 4);
            int dd[8] = {d0.x, d0.y, d0.z, d0.w, d1.x, d1.y, d1.z, d1.w};
#pragma unroll
            for (int k = 0; k < 8; ++k) {
                unsigned rel = (unsigned)(dd[k] - base);
                if (rel < (unsigned)rsz) rank[i + k] = atomicAdd(&lh[rel], 1);
            }
        }
        if (t == 0) {   // partial final 8-block of the chunk
            for (int i = e0 + ((e1 - e0) & ~7); i < e1; ++i) {
                unsigned rel = (unsigned)(dstv[i] - base);
                if (rel < (unsigned)rsz) rank[i] = atomicAdd(&lh[rel], 1);
            }
        }
        __syncthreads();
        int* outp = chist + (size_t)c * n + base;
        for (int i = t; i < rsz; i += 256) outp[i] = lh[i];
        return;
    }
    int lane = threadIdx.x & 63;
    int wave = threadIdx.x >> 6;
    int j2 = lane * 2;              // flattened out channel pair = head*32 + c
    int nbase = blockIdx.x * 64 + wave * 16;

    float2 wr[32];
#pragma unroll
    for (int k = 0; k < 32; ++k)
        wr[k] = *reinterpret_cast<const float2*>(W + k * 128 + j2);
    float2 as2 = *reinterpret_cast<const float2*>(a_src + j2);
    float2 ad2 = *reinterpret_cast<const float2*>(a_dst + j2);

    float xr[16];
#pragma unroll
    for (int m = 0; m < 16; ++m) {
        int node = nbase + m;
        xr[m] = (node < n) ? x[(size_t)node * 32 + (lane & 31)] : 0.f;
    }

#pragma unroll
    for (int m = 0; m < 16; ++m) {
        int node = nbase + m;
        if (node >= n) continue;     // wave-uniform guard
        float acc0 = 0.f, acc1 = 0.f;
#pragma unroll
        for (int k = 0; k < 32; ++k) {
            float xv = lane_bcast(xr[m], k);
            acc0 += xv * wr[k].x;
            acc1 += xv * wr[k].y;
        }
        *reinterpret_cast<__half2*>(h16 + (size_t)node * 128 + j2) =
            __floats2half2_rn(acc0, acc1);
        float ps = acc0 * as2.x + acc1 * as2.y;
        float pd = acc0 * ad2.x + acc1 * ad2.y;
#pragma unroll
        for (int mm = 1; mm < 16; mm <<= 1) {
            ps += __shfl_xor(ps, mm, 64);
            pd += __shfl_xor(pd, mm, 64);
        }
        if ((lane & 15) == 0) {
            int head = lane >> 4;
            alpha_src[node * 4 + head] = ps;
            alpha_dst[node * 4 + head] = pd;
        }
    }
}

// Zero-LDS GEMM (layers 1,2)
__global__ void __launch_bounds__(256)
k_gemm_alpha(const float* __restrict__ x, const float* __restrict__ W,
             const float* __restrict__ a_src, const float* __restrict__ a_dst,
             __half* __restrict__ h16, float* __restrict__ alpha_src,
             float* __restrict__ alpha_dst, int n) {
    int lane = threadIdx.x & 63;
    int wave = threadIdx.x >> 6;
    int j2 = lane * 2;
    int nbase = blockIdx.x * 64 + wave * 16;

    float2 wr[32];
#pragma unroll
    for (int k = 0; k < 32; ++k)
        wr[k] = *reinterpret_cast<const float2*>(W + k * 128 + j2);
    float2 as2 = *reinterpret_cast<const float2*>(a_src + j2);
    float2 ad2 = *reinterpret_cast<const float2*>(a_dst + j2);

    float xr[16];
#pragma unroll
    for (int m = 0; m < 16; ++m) {
        int node = nbase + m;
        xr[m] = (node < n) ? x[(size_t)node * 32 + (lane & 31)] : 0.f;
    }

#pragma unroll
    for (int m = 0; m < 16; ++m) {
        int node = nbase + m;
        if (node >= n) continue;
        float acc0 = 0.f, acc1 = 0.f;
#pragma unroll
        for (int k = 0; k < 32; ++k) {
            float xv = lane_bcast(xr[m], k);
            acc0 += xv * wr[k].x;
            acc1 += xv * wr[k].y;
        }
        *reinterpret_cast<__half2*>(h16 + (size_t)node * 128 + j2) =
            __floats2half2_rn(acc0, acc1);
        float ps = acc0 * as2.x + acc1 * as2.y;
        float pd = acc0 * ad2.x + acc1 * ad2.y;
#pragma unroll
        for (int mm = 1; mm < 16; mm <<= 1) {
            ps += __shfl_xor(ps, mm, 64);
            pd += __shfl_xor(pd, mm, 64);
        }
        if ((lane & 15) == 0) {
            int head = lane >> 4;
            alpha_src[node * 4 + head] = ps;
            alpha_dst[node * 4 + head] = pd;
        }
    }
}

__device__ __forceinline__ float lrelu_exp(float e) {
    e = e > 0.f ? e : 0.2f * e;
    return __expf(e);
}

// one wave per dst node; 4 edges per wave via 16-lane groups, 2 edges in flight
// per group (8 rows in flight/wave). Lane q loads uint4 = 8 fp16 channels.
// single-pass softmax + self loop + head-mean + bias + elu.
__global__ void k_agg(const __half* __restrict__ h16, const float* __restrict__ asrc,
                      const float* __restrict__ adst, const int* __restrict__ rowst,
                      const int* __restrict__ col, const float* __restrict__ bias,
                      float* __restrict__ out, int n) {
    int wid = (int)((blockIdx.x * (size_t)blockDim.x + threadIdx.x) >> 6);
    if (wid >= n) return;
    int lane = threadIdx.x & 63;
    int g = lane >> 4;
    int q = lane & 15;
    int head = q >> 2;
    float ad = adst[wid * 4 + head];

    float acc[8] = {0.f, 0.f, 0.f, 0.f, 0.f, 0.f, 0.f, 0.f};
    float s = 0.f;

    if (g == 0) {  // self loop counted once (group 0)
        float w = lrelu_exp(asrc[wid * 4 + head] + ad);
        uint4 v = *reinterpret_cast<const uint4*>(h16 + (size_t)wid * 128 + q * 8);
        const __half2* hp = reinterpret_cast<const __half2*>(&v);
        s = w;
#pragma unroll
        for (int k = 0; k < 4; ++k) {
            float2 f = __half22float2(hp[k]);
            acc[2 * k]     += w * f.x;
            acc[2 * k + 1] += w * f.y;
        }
    }

    int beg = rowst[wid], end = rowst[wid + 1];
    int i = beg + g;
    for (; i + 4 < end; i += 8) {
        int s0 = col[i];
        int s1 = col[i + 4];
        float x0 = asrc[s0 * 4 + head];
        float x1 = asrc[s1 * 4 + head];
        uint4 v0 = *reinterpret_cast<const uint4*>(h16 + (size_t)s0 * 128 + q * 8);
        uint4 v1 = *reinterpret_cast<const uint4*>(h16 + (size_t)s1 * 128 + q * 8);
        float w0 = lrelu_exp(x0 + ad);
        float w1 = lrelu_exp(x1 + ad);
        s += w0 + w1;
        const __half2* h0 = reinterpret_cast<const __half2*>(&v0);
        const __half2* h1 = reinterpret_cast<const __half2*>(&v1);
#pragma unroll
        for (int k = 0; k < 4; ++k) {
            float2 f0 = __half22float2(h0[k]);
            float2 f1 = __half22float2(h1[k]);
            acc[2 * k]     += w0 * f0.x + w1 * f1.x;
            acc[2 * k + 1] += w0 * f0.y + w1 * f1.y;
        }
    }
    if (i < end) {
        int s0 = col[i];
        float w = lrelu_exp(asrc[s0 * 4 + head] + ad);
        uint4 v = *reinterpret_cast<const uint4*>(h16 + (size_t)s0 * 128 + q * 8);
        const __half2* hp = reinterpret_cast<const __half2*>(&v);
        s += w;
#pragma unroll
        for (int k = 0; k < 4; ++k) {
            float2 f = __half22float2(hp[k]);
            acc[2 * k]     += w * f.x;
            acc[2 * k + 1] += w * f.y;
        }
    }

    s += __shfl_xor(s, 16, 64);
    s += __shfl_xor(s, 32, 64);
#pragma unroll
    for (int k = 0; k < 8; ++k) {
        acc[k] += __shfl_xor(acc[k], 16, 64);
        acc[k] += __shfl_xor(acc[k], 32, 64);
    }
    float inv = 1.f / s;
#pragma unroll
    for (int k = 0; k < 8; ++k) acc[k] *= inv;
#pragma unroll
    for (int k = 0; k < 8; ++k) {
        acc[k] += __shfl_xor(acc[k], 4, 64);
        acc[k] += __shfl_xor(acc[k], 8, 64);
    }
    if (lane < 4) {
        float o[8];
#pragma unroll
        for (int k = 0; k < 8; ++k) {
            float v = acc[k] * 0.25f + bias[lane * 8 + k];
            o[k] = v > 0.f ? v : (__expf(v) - 1.f);
        }
        float4* op = reinterpret_cast<float4*>(&out[(size_t)wid * 32 + lane * 8]);
        op[0] = make_float4(o[0], o[1], o[2], o[3]);
        op[1] = make_float4(o[4], o[5], o[6], o[7]);
    }
}

// ---------------- launch ----------------

extern "C" void kernel_launch(void* const* d_in, const int* in_sizes, int n_in,
                              void* d_out, int out_size, void* d_ws, size_t ws_size,
                              hipStream_t stream) {
    const float* x       = (const float*)d_in[0];
    const int*   ei      = (const int*)d_in[1];   // [2,E] int32
    const float* Ws      = (const float*)d_in[3]; // [3,32,128]
    const float* att_src = (const float*)d_in[4]; // [3,4,32]
    const float* att_dst = (const float*)d_in[5];
    const float* bias    = (const float*)d_in[6]; // [3,32]

    int N = in_sizes[0] / 32;
    int E = in_sizes[1] / 2;
    const int* srcv = ei;
    const int* dstv = ei + E;

    // workspace layout (~71MB)
    float* fws   = (float*)d_ws;
    __half* h16  = (__half*)fws;                        // N*128 halves
    float* asrc  = (float*)(h16 + (size_t)N * 128);     // N*4
    float* adst  = asrc + (size_t)N * 4;                // N*4
    float* xbuf  = adst + (size_t)N * 4;                // N*32
    int*   deg    = (int*)(xbuf + (size_t)N * 32);      // N
    int*   rowst  = deg + N;                            // N+1
    int*   bsums  = rowst + N + 1;                      // 512
    int*   boffs  = bsums + 512;                        // 512
    int*   col    = boffs + 512;                        // E
    int*   rank   = col + E;                            // E
    int*   chist  = rank + E;                           // NCHUNK*N

    int nb256 = (N + 255) / 256;                         // <=512 for scan2
    int gemmBlocks = (N + 63) / 64;
    int rangeSize = (N + NRANGE - 1) / NRANGE;           // 6250 (<=RSIZE_MAX)
    int chunkSize = (((E + NCHUNK - 1) / NCHUNK) + 7) & ~7;   // 40000, mult of 8
    int blocksPerChunk = (chunkSize + 256 * SCAT_PER - 1) / (256 * SCAT_PER);

    // layer 0: GEMM+alpha fused with LDS histogram (+rank capture)
    k_gemm_hist<<<gemmBlocks + NRANGE * NCHUNK, 256, 0, stream>>>(
        x, Ws, att_src, att_dst, h16, asrc, adst, N,
        dstv, E, chunkSize, rangeSize, chist, rank, gemmBlocks);
    k_chist_scan<<<nb256, 256, 0, stream>>>(chist, N, deg);
    k_scan1<<<nb256, 256, 0, stream>>>(deg, N, bsums);
    k_scan2<<<1, 512, 0, stream>>>(bsums, nb256, boffs);
    k_scan3<<<nb256, 256, 0, stream>>>(deg, N, boffs, rowst);
    k_scatter<<<NCHUNK * blocksPerChunk, 256, 0, stream>>>(
        srcv, dstv, rank, rowst, chist, N, E, chunkSize, blocksPerChunk, col);
    k_agg<<<(N + 3) / 4, 256, 0, stream>>>(
        h16, asrc, adst, rowst, col, bias, (float*)xbuf, N);

    for (int l = 1; l < 3; ++l) {
        float* xout = (l == 2) ? (float*)d_out : xbuf;
        k_gemm_alpha<<<gemmBlocks, 256, 0, stream>>>(
            xbuf, Ws + (size_t)l * 32 * 128, att_src + l * 128, att_dst + l * 128,
            h16, asrc, adst, N);
        k_agg<<<(N + 3) / 4, 256, 0, stream>>>(
            h16, asrc, adst, rowst, col, bias + l * 32, xout, N);
    }
}